// Round 1
// baseline (363.329 us; speedup 1.0000x reference)
//
#include <hip/hip_runtime.h>

typedef __bf16 bf16;
typedef __attribute__((ext_vector_type(8))) __bf16 bf16x8;
typedef __attribute__((ext_vector_type(4))) float f32x4;

#define S 2048
#define DMODEL 512
#define NH 8
#define DH 64
#define DFF 2048
#define MAXLEN 16384
#define LN_EPS 1e-5f
#define LPAD 40

// ---------------- generic bf16 MFMA GEMM: C = A[M,K] @ Bt[N,K]^T (+bias)(+relu) ----------------
// flags: bit0 = relu, bit1 = bf16 output (else fp32)
__global__ __launch_bounds__(256) void gemm_k(
    const bf16* __restrict__ A, long sAz, int lda,
    const bf16* __restrict__ B, long sBz, int ldb,
    void* __restrict__ C, long sCz, int ldc,
    const float* __restrict__ bias, int flags,
    int M, int N, int K)
{
  __shared__ bf16 lsA[128 * LPAD];
  __shared__ bf16 lsB[128 * LPAD];
  const int z = blockIdx.z;
  A += (long)z * sAz;
  B += (long)z * sBz;
  const int m0 = blockIdx.y * 128, n0 = blockIdx.x * 128;
  const int tid = threadIdx.x;
  const int lane = tid & 63, w = tid >> 6;
  const int wr = (w >> 1) * 64, wc = (w & 1) * 64;
  const int r15 = lane & 15, kg = lane >> 4;
  f32x4 acc[4][4] = {};
  for (int k0 = 0; k0 < K; k0 += 32) {
#pragma unroll
    for (int i = 0; i < 2; ++i) {
      int cid = tid + i * 256;
      int row = cid >> 2, kb = (cid & 3) * 8;
      *(bf16x8*)&lsA[row * LPAD + kb] = *(const bf16x8*)&A[(long)(m0 + row) * lda + (k0 + kb)];
      bf16x8 bv = {};
      if (n0 + row < N) bv = *(const bf16x8*)&B[(long)(n0 + row) * ldb + (k0 + kb)];
      *(bf16x8*)&lsB[row * LPAD + kb] = bv;
    }
    __syncthreads();
    bf16x8 af[4], bfr[4];
#pragma unroll
    for (int mi = 0; mi < 4; ++mi) af[mi] = *(const bf16x8*)&lsA[(wr + mi * 16 + r15) * LPAD + kg * 8];
#pragma unroll
    for (int ni = 0; ni < 4; ++ni) bfr[ni] = *(const bf16x8*)&lsB[(wc + ni * 16 + r15) * LPAD + kg * 8];
#pragma unroll
    for (int mi = 0; mi < 4; ++mi)
#pragma unroll
      for (int ni = 0; ni < 4; ++ni)
        acc[mi][ni] = __builtin_amdgcn_mfma_f32_16x16x32_bf16(af[mi], bfr[ni], acc[mi][ni], 0, 0, 0);
    __syncthreads();
  }
#pragma unroll
  for (int mi = 0; mi < 4; ++mi)
#pragma unroll
    for (int ni = 0; ni < 4; ++ni) {
      int col = n0 + wc + ni * 16 + r15;
      if (col >= N) continue;
      float bv = bias ? bias[col] : 0.f;
#pragma unroll
      for (int r = 0; r < 4; ++r) {
        int row = m0 + wr + mi * 16 + kg * 4 + r;
        float v = acc[mi][ni][r] + bv;
        if (flags & 1) v = fmaxf(v, 0.f);
        if (flags & 2) ((bf16*)C)[(long)z * sCz + (long)row * ldc + col] = (bf16)v;
        else           ((float*)C)[(long)z * sCz + (long)row * ldc + col] = v;
      }
    }
}

// ---------------- scores: P = bf16( (Q@K^T + Srel) / 8 ), Srel gathered from QEr ----------------
__global__ __launch_bounds__(256) void scores_k(
    const bf16* __restrict__ q, const bf16* __restrict__ kk,
    const bf16* __restrict__ qer, bf16* __restrict__ P)
{
  __shared__ bf16 lsA[128 * LPAD];
  __shared__ bf16 lsB[128 * LPAD];
  const int h = blockIdx.z;
  const bf16* A = q + h * DH;
  const bf16* B = kk + h * DH;
  const int m0 = blockIdx.y * 128, n0 = blockIdx.x * 128;
  const int tid = threadIdx.x;
  const int lane = tid & 63, w = tid >> 6;
  const int wr = (w >> 1) * 64, wc = (w & 1) * 64;
  const int r15 = lane & 15, kg = lane >> 4;
  f32x4 acc[4][4] = {};
  for (int k0 = 0; k0 < DH; k0 += 32) {
#pragma unroll
    for (int i = 0; i < 2; ++i) {
      int cid = tid + i * 256;
      int row = cid >> 2, kb = (cid & 3) * 8;
      *(bf16x8*)&lsA[row * LPAD + kb] = *(const bf16x8*)&A[(long)(m0 + row) * DMODEL + (k0 + kb)];
      *(bf16x8*)&lsB[row * LPAD + kb] = *(const bf16x8*)&B[(long)(n0 + row) * DMODEL + (k0 + kb)];
    }
    __syncthreads();
    bf16x8 af[4], bfr[4];
#pragma unroll
    for (int mi = 0; mi < 4; ++mi) af[mi] = *(const bf16x8*)&lsA[(wr + mi * 16 + r15) * LPAD + kg * 8];
#pragma unroll
    for (int ni = 0; ni < 4; ++ni) bfr[ni] = *(const bf16x8*)&lsB[(wc + ni * 16 + r15) * LPAD + kg * 8];
#pragma unroll
    for (int mi = 0; mi < 4; ++mi)
#pragma unroll
      for (int ni = 0; ni < 4; ++ni)
        acc[mi][ni] = __builtin_amdgcn_mfma_f32_16x16x32_bf16(af[mi], bfr[ni], acc[mi][ni], 0, 0, 0);
    __syncthreads();
  }
  const long hb = (long)h * S * S;
#pragma unroll
  for (int mi = 0; mi < 4; ++mi)
#pragma unroll
    for (int ni = 0; ni < 4; ++ni) {
      int cg = n0 + wc + ni * 16 + r15;
#pragma unroll
      for (int r = 0; r < 4; ++r) {
        int rg = m0 + wr + mi * 16 + kg * 4 + r;
        float srel;
        if (cg == rg + 1)      srel = 0.f;
        else if (cg <= rg)     srel = (float)qer[hb + (long)rg * S + (cg + (S - 1) - rg)];
        else                   srel = (float)qer[hb + (long)(rg + 1) * S + (cg - rg - 2)];
        P[hb + (long)rg * S + cg] = (bf16)((acc[mi][ni][r] + srel) * 0.125f);
      }
    }
}

// ---------------- row softmax in-place on bf16 [NH*S rows][S] ----------------
__global__ __launch_bounds__(256) void softmax_k(bf16* __restrict__ P)
{
  const long base = (long)blockIdx.x * S;
  const int tid = threadIdx.x;
  const int lane = tid & 63, w = tid >> 6;
  __shared__ float red[4];
  bf16x8 v = *(const bf16x8*)&P[base + tid * 8];
  float f[8];
  float m = -1e30f;
#pragma unroll
  for (int i = 0; i < 8; ++i) { f[i] = (float)v[i]; m = fmaxf(m, f[i]); }
  for (int o = 32; o; o >>= 1) m = fmaxf(m, __shfl_xor(m, o));
  if (lane == 0) red[w] = m;
  __syncthreads();
  m = fmaxf(fmaxf(red[0], red[1]), fmaxf(red[2], red[3]));
  __syncthreads();
  float sum = 0.f;
#pragma unroll
  for (int i = 0; i < 8; ++i) { f[i] = expf(f[i] - m); sum += f[i]; }
  for (int o = 32; o; o >>= 1) sum += __shfl_xor(sum, o);
  if (lane == 0) red[w] = sum;
  __syncthreads();
  sum = red[0] + red[1] + red[2] + red[3];
  float inv = 1.f / sum;
  bf16x8 ov;
#pragma unroll
  for (int i = 0; i < 8; ++i) ov[i] = (bf16)(f[i] * inv);
  *(bf16x8*)&P[base + tid * 8] = ov;
}

// ---------------- layernorms ----------------
__device__ __forceinline__ float blk_sum(float v, float* red) {
  for (int o = 32; o; o >>= 1) v += __shfl_xor(v, o);
  int tid = threadIdx.x;
  if ((tid & 63) == 0) red[tid >> 6] = v;
  __syncthreads();
  v = red[0] + red[1] + red[2] + red[3];
  __syncthreads();
  return v;
}

// y[b*S+s][d] = bf16( LN(src[s][b][:] + sa[s][:]) * g + be )
__global__ __launch_bounds__(256) void ln1_k(
    const float* __restrict__ src, const float* __restrict__ sa,
    const float* __restrict__ g, const float* __restrict__ be, bf16* __restrict__ y)
{
  __shared__ float red[4];
  const int row = blockIdx.x;
  const int b = row >> 11, s2 = row & 2047;
  const float* xs = src + (long)s2 * (2 * DMODEL) + b * DMODEL;
  const float* ss = sa + (long)s2 * DMODEL;
  const int tid = threadIdx.x;
  float a0 = xs[tid] + ss[tid];
  float a1 = xs[tid + 256] + ss[tid + 256];
  float sum = blk_sum(a0 + a1, red);
  float sq  = blk_sum(a0 * a0 + a1 * a1, red);
  float mu = sum * (1.f / DMODEL);
  float var = sq * (1.f / DMODEL) - mu * mu;
  float rs = rsqrtf(var + LN_EPS);
  y[(long)row * DMODEL + tid]       = (bf16)((a0 - mu) * rs * g[tid] + be[tid]);
  y[(long)row * DMODEL + tid + 256] = (bf16)((a1 - mu) * rs * g[tid + 256] + be[tid + 256]);
}

// out[s][b][d] = LN( y[b*S+s][:] + ff[b*S+s][:] ) * g + be   (fp32 out)
__global__ __launch_bounds__(256) void ln2_k(
    const bf16* __restrict__ y, const float* __restrict__ ff,
    const float* __restrict__ g, const float* __restrict__ be, float* __restrict__ out)
{
  __shared__ float red[4];
  const int row = blockIdx.x;
  const int b = row >> 11, s2 = row & 2047;
  const int tid = threadIdx.x;
  float a0 = (float)y[(long)row * DMODEL + tid]       + ff[(long)row * DMODEL + tid];
  float a1 = (float)y[(long)row * DMODEL + tid + 256] + ff[(long)row * DMODEL + tid + 256];
  float sum = blk_sum(a0 + a1, red);
  float sq  = blk_sum(a0 * a0 + a1 * a1, red);
  float mu = sum * (1.f / DMODEL);
  float var = sq * (1.f / DMODEL) - mu * mu;
  float rs = rsqrtf(var + LN_EPS);
  float* o = out + (long)s2 * (2 * DMODEL) + b * DMODEL;
  o[tid]       = (a0 - mu) * rs * g[tid] + be[tid];
  o[tid + 256] = (a1 - mu) * rs * g[tid + 256] + be[tid + 256];
}

// ---------------- converts / transposes ----------------
__global__ __launch_bounds__(256) void conv_x0_k(const float* __restrict__ src, bf16* __restrict__ x0b)
{
  long i = (long)blockIdx.x * 256 + threadIdx.x;
  int s2 = (int)(i >> 9), d = (int)(i & 511);
  x0b[i] = (bf16)src[(long)s2 * (2 * DMODEL) + d];
}

__global__ __launch_bounds__(256) void conv_er_k(const float* __restrict__ Er, bf16* __restrict__ erS)
{
  long i = (long)blockIdx.x * 256 + threadIdx.x;
  erS[i] = (bf16)Er[(long)(MAXLEN - S) * DH + i];
}

// fp32 in[R][Cn] -> bf16 out[Cn][R]
__global__ void tr_f2b_k(const float* __restrict__ in, bf16* __restrict__ out, int R, int Cn)
{
  __shared__ float t[32][33];
  int c0 = blockIdx.x * 32, r0 = blockIdx.y * 32;
  int tx = threadIdx.x, ty = threadIdx.y;
#pragma unroll
  for (int i = 0; i < 32; i += 8) t[ty + i][tx] = in[(long)(r0 + ty + i) * Cn + c0 + tx];
  __syncthreads();
#pragma unroll
  for (int i = 0; i < 32; i += 8) out[(long)(c0 + ty + i) * R + r0 + tx] = (bf16)t[tx][ty + i];
}

// bf16 in[R][Cn] -> bf16 out[Cn][R]
__global__ void tr_b2b_k(const bf16* __restrict__ in, bf16* __restrict__ out, int R, int Cn)
{
  __shared__ bf16 t[32][34];
  int c0 = blockIdx.x * 32, r0 = blockIdx.y * 32;
  int tx = threadIdx.x, ty = threadIdx.y;
#pragma unroll
  for (int i = 0; i < 32; i += 8) t[ty + i][tx] = in[(long)(r0 + ty + i) * Cn + c0 + tx];
  __syncthreads();
#pragma unroll
  for (int i = 0; i < 32; i += 8) out[(long)(c0 + ty + i) * R + r0 + tx] = t[tx][ty + i];
}

// ---------------- host launch ----------------
extern "C" void kernel_launch(void* const* d_in, const int* in_sizes, int n_in,
                              void* d_out, int out_size, void* d_ws, size_t ws_size,
                              hipStream_t stream)
{
  const float* src = (const float*)d_in[0];
  const float* Wq  = (const float*)d_in[1];
  const float* bq  = (const float*)d_in[2];
  const float* Wk  = (const float*)d_in[3];
  const float* bk  = (const float*)d_in[4];
  const float* Wv  = (const float*)d_in[5];
  const float* bv  = (const float*)d_in[6];
  const float* Er  = (const float*)d_in[7];
  const float* W1  = (const float*)d_in[8];
  const float* b1  = (const float*)d_in[9];
  const float* W2  = (const float*)d_in[10];
  const float* b2  = (const float*)d_in[11];
  const float* g1  = (const float*)d_in[12];
  const float* be1 = (const float*)d_in[13];
  const float* g2  = (const float*)d_in[14];
  const float* be2 = (const float*)d_in[15];

  char* wp = (char*)d_ws;
  auto alloc = [&](size_t bytes) { char* p = wp; wp += (bytes + 255) & ~(size_t)255; return p; };

  bf16* x0b = (bf16*)alloc((size_t)S * DMODEL * 2);
  bf16* wqT = (bf16*)alloc((size_t)DMODEL * DMODEL * 2);
  bf16* wkT = (bf16*)alloc((size_t)DMODEL * DMODEL * 2);
  bf16* wvT = (bf16*)alloc((size_t)DMODEL * DMODEL * 2);
  bf16* w1T = (bf16*)alloc((size_t)DFF * DMODEL * 2);
  bf16* w2T = (bf16*)alloc((size_t)DMODEL * DFF * 2);
  bf16* erS = (bf16*)alloc((size_t)S * DH * 2);
  bf16* qb  = (bf16*)alloc((size_t)S * DMODEL * 2);
  bf16* kb  = (bf16*)alloc((size_t)S * DMODEL * 2);
  bf16* vb  = (bf16*)alloc((size_t)S * DMODEL * 2);
  bf16* vt  = (bf16*)alloc((size_t)DMODEL * S * 2);
  bf16* qer = (bf16*)alloc((size_t)NH * S * S * 2);
  bf16* p   = (bf16*)alloc((size_t)NH * S * S * 2);
  float* sa = (float*)alloc((size_t)S * DMODEL * 4);
  bf16* yb  = (bf16*)alloc((size_t)2 * S * DMODEL * 2);
  bf16* h1  = (bf16*)alloc((size_t)2 * S * DFF * 2);
  float* ff = (float*)alloc((size_t)2 * S * DMODEL * 4);

  dim3 tb(32, 8);

  // prep: converts + weight transposes
  conv_x0_k<<<(S * DMODEL) / 256, 256, 0, stream>>>(src, x0b);
  conv_er_k<<<(S * DH) / 256, 256, 0, stream>>>(Er, erS);
  tr_f2b_k<<<dim3(DMODEL / 32, DMODEL / 32), tb, 0, stream>>>(Wq, wqT, DMODEL, DMODEL);
  tr_f2b_k<<<dim3(DMODEL / 32, DMODEL / 32), tb, 0, stream>>>(Wk, wkT, DMODEL, DMODEL);
  tr_f2b_k<<<dim3(DMODEL / 32, DMODEL / 32), tb, 0, stream>>>(Wv, wvT, DMODEL, DMODEL);
  tr_f2b_k<<<dim3(DFF / 32, DMODEL / 32), tb, 0, stream>>>(W1, w1T, DMODEL, DFF);
  tr_f2b_k<<<dim3(DMODEL / 32, DFF / 32), tb, 0, stream>>>(W2, w2T, DFF, DMODEL);

  // QKV (batch 0 only)
  gemm_k<<<dim3(4, 16, 1), 256, 0, stream>>>(x0b, 0, DMODEL, wqT, 0, DMODEL, qb, 0, DMODEL, bq, 2, S, DMODEL, DMODEL);
  gemm_k<<<dim3(4, 16, 1), 256, 0, stream>>>(x0b, 0, DMODEL, wkT, 0, DMODEL, kb, 0, DMODEL, bk, 2, S, DMODEL, DMODEL);
  gemm_k<<<dim3(4, 16, 1), 256, 0, stream>>>(x0b, 0, DMODEL, wvT, 0, DMODEL, vb, 0, DMODEL, bv, 2, S, DMODEL, DMODEL);

  // V transpose -> [DMODEL][S]
  tr_b2b_k<<<dim3(DMODEL / 32, S / 32), tb, 0, stream>>>(vb, vt, S, DMODEL);

  // QEr[h] = Q_h @ ErS^T  (bf16 out)
  gemm_k<<<dim3(16, 16, 8), 256, 0, stream>>>(qb, DH, DMODEL, erS, 0, DH, qer, (long)S * S, S, nullptr, 2, S, S, DH);

  // scores + skew
  scores_k<<<dim3(16, 16, 8), 256, 0, stream>>>(qb, kb, qer, p);

  // softmax
  softmax_k<<<NH * S, 256, 0, stream>>>(p);

  // PV: sa[:, h*64:(h+1)*64] = P_h @ V_h
  gemm_k<<<dim3(1, 16, 8), 256, 0, stream>>>(p, (long)S * S, S, vt, (long)DH * S, S, sa, DH, DMODEL, nullptr, 0, S, DH, S);

  // LN1 -> y (bf16), rows ordered [b][s]
  ln1_k<<<2 * S, 256, 0, stream>>>(src, sa, g1, be1, yb);

  // FFN
  gemm_k<<<dim3(DFF / 128, (2 * S) / 128, 1), 256, 0, stream>>>(yb, 0, DMODEL, w1T, 0, DMODEL, h1, 0, DFF, b1, 3, 2 * S, DFF, DMODEL);
  gemm_k<<<dim3(DMODEL / 128, (2 * S) / 128, 1), 256, 0, stream>>>(h1, 0, DFF, w2T, 0, DFF, ff, 0, DMODEL, b2, 0, 2 * S, DMODEL, DFF);

  // LN2 -> out
  ln2_k<<<2 * S, 256, 0, stream>>>(yb, ff, g2, be2, (float*)d_out);
}

// Round 2
// 326.644 us; speedup vs baseline: 1.1123x; 1.1123x over previous
//
#include <hip/hip_runtime.h>

typedef __bf16 bf16;
typedef __attribute__((ext_vector_type(8))) __bf16 bf16x8;
typedef __attribute__((ext_vector_type(4))) float f32x4;

#define S 2048
#define DMODEL 512
#define NH 8
#define DH 64
#define DFF 2048
#define MAXLEN 16384
#define LN_EPS 1e-5f
#define LPAD 40
#define BC 128

// ---------------- generic bf16 MFMA GEMM: C = A[M,K] @ Bt[N,K]^T (+bias)(+relu) ----------------
// flags: bit0 = relu, bit1 = bf16 output (else fp32)
__global__ __launch_bounds__(256) void gemm_k(
    const bf16* __restrict__ A, long sAz, int lda,
    const bf16* __restrict__ B, long sBz, int ldb,
    void* __restrict__ C, long sCz, int ldc,
    const float* __restrict__ bias, int flags,
    int M, int N, int K)
{
  __shared__ bf16 lsA[128 * LPAD];
  __shared__ bf16 lsB[128 * LPAD];
  const int z = blockIdx.z;
  A += (long)z * sAz;
  B += (long)z * sBz;
  const int m0 = blockIdx.y * 128, n0 = blockIdx.x * 128;
  const int tid = threadIdx.x;
  const int lane = tid & 63, w = tid >> 6;
  const int wr = (w >> 1) * 64, wc = (w & 1) * 64;
  const int r15 = lane & 15, kg = lane >> 4;
  f32x4 acc[4][4] = {};
  for (int k0 = 0; k0 < K; k0 += 32) {
#pragma unroll
    for (int i = 0; i < 2; ++i) {
      int cid = tid + i * 256;
      int row = cid >> 2, kb = (cid & 3) * 8;
      *(bf16x8*)&lsA[row * LPAD + kb] = *(const bf16x8*)&A[(long)(m0 + row) * lda + (k0 + kb)];
      bf16x8 bv = {};
      if (n0 + row < N) bv = *(const bf16x8*)&B[(long)(n0 + row) * ldb + (k0 + kb)];
      *(bf16x8*)&lsB[row * LPAD + kb] = bv;
    }
    __syncthreads();
    bf16x8 af[4], bfr[4];
#pragma unroll
    for (int mi = 0; mi < 4; ++mi) af[mi] = *(const bf16x8*)&lsA[(wr + mi * 16 + r15) * LPAD + kg * 8];
#pragma unroll
    for (int ni = 0; ni < 4; ++ni) bfr[ni] = *(const bf16x8*)&lsB[(wc + ni * 16 + r15) * LPAD + kg * 8];
#pragma unroll
    for (int mi = 0; mi < 4; ++mi)
#pragma unroll
      for (int ni = 0; ni < 4; ++ni)
        acc[mi][ni] = __builtin_amdgcn_mfma_f32_16x16x32_bf16(af[mi], bfr[ni], acc[mi][ni], 0, 0, 0);
    __syncthreads();
  }
#pragma unroll
  for (int mi = 0; mi < 4; ++mi)
#pragma unroll
    for (int ni = 0; ni < 4; ++ni) {
      int col = n0 + wc + ni * 16 + r15;
      if (col >= N) continue;
      float bv = bias ? bias[col] : 0.f;
#pragma unroll
      for (int r = 0; r < 4; ++r) {
        int row = m0 + wr + mi * 16 + kg * 4 + r;
        float v = acc[mi][ni][r] + bv;
        if (flags & 1) v = fmaxf(v, 0.f);
        if (flags & 2) ((bf16*)C)[(long)z * sCz + (long)row * ldc + col] = (bf16)v;
        else           ((float*)C)[(long)z * sCz + (long)row * ldc + col] = v;
      }
    }
}

// ---------------- fused attention: scores(+skew)+online softmax+PV ----------------
// grid (64, NH): blockIdx.x -> rb = bx>>1 (64-row block), sp = bx&1 (column half)
// 4 waves, wave w owns q-rows [r0 + 16w, r0 + 16w + 16)
// partials: pO[sp][h][S][DH], pM/pL[sp][h][S]
__global__ __launch_bounds__(256) void attn_k(
    const bf16* __restrict__ qg, const bf16* __restrict__ kgl, const bf16* __restrict__ vtg,
    const bf16* __restrict__ qer,
    float* __restrict__ pO, float* __restrict__ pM, float* __restrict__ pL)
{
  __shared__ bf16 Kl[BC][72];        // K tile [c][k]
  __shared__ bf16 Vl[DH][BC + 8];    // V^T tile [d][c]
  __shared__ bf16 Pl[4][16][BC + 8]; // per-wave P [row][c]
  const int bx = blockIdx.x;
  const int h = blockIdx.y;
  const int rb = bx >> 1, sp = bx & 1;
  const int r0 = rb * 64;
  const int c_base = sp * (S / 2);
  const int tid = threadIdx.x, lane = tid & 63, w = tid >> 6;
  const int r15 = lane & 15, g = lane >> 4;
  const long hb = (long)h * S * S;

  // persistent Q A-frags: row = r0 + 16w + r15, k = kc*32 + g*8 + j
  bf16x8 qf[2];
  {
    const bf16* qrow = qg + (long)(r0 + w * 16 + r15) * DMODEL + h * DH;
    qf[0] = *(const bf16x8*)&qrow[g * 8];
    qf[1] = *(const bf16x8*)&qrow[32 + g * 8];
  }
  f32x4 Oacc[4] = {};
  float mrow[4], lrow[4];
#pragma unroll
  for (int r = 0; r < 4; ++r) { mrow[r] = -1e30f; lrow[r] = 0.f; }

  const int rGlob = r0 + w * 16 + 4 * g; // +r

  for (int t = 0; t < (S / 2) / BC; ++t) {
    const int c0 = c_base + t * BC;
    __syncthreads();
    // stage K tile: 128 rows x 64
#pragma unroll
    for (int i = 0; i < 4; ++i) {
      int cid = tid + i * 256;
      int row = cid >> 3, ch = cid & 7;
      *(bf16x8*)&Kl[row][ch * 8] = *(const bf16x8*)&kgl[(long)(c0 + row) * DMODEL + h * DH + ch * 8];
    }
    // stage V^T tile: 64 rows x 128
#pragma unroll
    for (int i = 0; i < 4; ++i) {
      int cid = tid + i * 256;
      int row = cid >> 4, ch = cid & 15;
      *(bf16x8*)&Vl[row][ch * 8] = *(const bf16x8*)&vtg[(long)(h * DH + row) * S + c0 + ch * 8];
    }
    __syncthreads();

    // QK^T: sc[ni] = 16x16 subtile (rows of this wave, cols c0+16ni..)
    f32x4 sc[8];
#pragma unroll
    for (int ni = 0; ni < 8; ++ni) {
      bf16x8 b0 = *(const bf16x8*)&Kl[ni * 16 + r15][g * 8];
      bf16x8 b1 = *(const bf16x8*)&Kl[ni * 16 + r15][32 + g * 8];
      f32x4 a = {};
      a = __builtin_amdgcn_mfma_f32_16x16x32_bf16(qf[0], b0, a, 0, 0, 0);
      a = __builtin_amdgcn_mfma_f32_16x16x32_bf16(qf[1], b1, a, 0, 0, 0);
      sc[ni] = a;
    }

    // add Srel (skew gather from qer) and scale by 1/8
#pragma unroll
    for (int ni = 0; ni < 8; ++ni) {
      int cg = c0 + ni * 16 + r15;
#pragma unroll
      for (int r = 0; r < 4; ++r) {
        int rg = rGlob + r;
        float srel;
        if (cg == rg + 1)      srel = 0.f;
        else if (cg <= rg)     srel = (float)qer[hb + (long)rg * S + (cg + (S - 1) - rg)];
        else                   srel = (float)qer[hb + (long)(rg + 1) * S + (cg - rg - 2)];
        sc[ni][r] = (sc[ni][r] + srel) * 0.125f;
      }
    }

    // online softmax
    float tmax[4];
#pragma unroll
    for (int r = 0; r < 4; ++r) {
      float m = sc[0][r];
#pragma unroll
      for (int ni = 1; ni < 8; ++ni) m = fmaxf(m, sc[ni][r]);
      tmax[r] = m;
    }
#pragma unroll
    for (int o = 1; o < 16; o <<= 1)
#pragma unroll
      for (int r = 0; r < 4; ++r) tmax[r] = fmaxf(tmax[r], __shfl_xor(tmax[r], o));

    float alpha[4], tsum[4];
#pragma unroll
    for (int r = 0; r < 4; ++r) {
      float mn = fmaxf(mrow[r], tmax[r]);
      alpha[r] = expf(mrow[r] - mn);
      mrow[r] = mn;
      tsum[r] = 0.f;
    }
#pragma unroll
    for (int ni = 0; ni < 8; ++ni)
#pragma unroll
      for (int r = 0; r < 4; ++r) {
        float p = expf(sc[ni][r] - mrow[r]);
        tsum[r] += p;
        Pl[w][4 * g + r][ni * 16 + r15] = (bf16)p;
      }
#pragma unroll
    for (int o = 1; o < 16; o <<= 1)
#pragma unroll
      for (int r = 0; r < 4; ++r) tsum[r] += __shfl_xor(tsum[r], o);
#pragma unroll
    for (int r = 0; r < 4; ++r) lrow[r] = lrow[r] * alpha[r] + tsum[r];
#pragma unroll
    for (int no = 0; no < 4; ++no)
#pragma unroll
      for (int r = 0; r < 4; ++r) Oacc[no][r] *= alpha[r];

    __syncthreads(); // P visible wave-wide (and keeps waves lockstep before restage)

    // PV: O[16x64] += P[16x128] @ V[128x64]
#pragma unroll
    for (int kc = 0; kc < 4; ++kc) {
      bf16x8 af = *(const bf16x8*)&Pl[w][r15][kc * 32 + g * 8];
#pragma unroll
      for (int no = 0; no < 4; ++no) {
        bf16x8 bv = *(const bf16x8*)&Vl[no * 16 + r15][kc * 32 + g * 8];
        Oacc[no] = __builtin_amdgcn_mfma_f32_16x16x32_bf16(af, bv, Oacc[no], 0, 0, 0);
      }
    }
  }

  // write partials
  const long ob = ((long)sp * NH + h) * S * DH;
#pragma unroll
  for (int no = 0; no < 4; ++no)
#pragma unroll
    for (int r = 0; r < 4; ++r)
      pO[ob + (long)(rGlob + r) * DH + no * 16 + r15] = Oacc[no][r];
  if (r15 == 0) {
    const long sb = ((long)sp * NH + h) * S;
#pragma unroll
    for (int r = 0; r < 4; ++r) {
      pM[sb + rGlob + r] = mrow[r];
      pL[sb + rGlob + r] = lrow[r];
    }
  }
}

// ---------------- merge the two column-half partials -> sa[r][DMODEL] (f32) ----------------
__global__ __launch_bounds__(256) void merge_k(
    const float* __restrict__ pO, const float* __restrict__ pM, const float* __restrict__ pL,
    float* __restrict__ sa)
{
  int i = blockIdx.x * 256 + threadIdx.x;
  int r = i >> 9, col = i & 511;
  int h = col >> 6, d = col & 63;
  long i0 = (long)h * S + r;
  float m0 = pM[i0], m1 = pM[(long)NH * S + i0];
  float M = fmaxf(m0, m1);
  float e0 = expf(m0 - M), e1 = expf(m1 - M);
  float l = pL[i0] * e0 + pL[(long)NH * S + i0] * e1;
  long o0 = ((long)h * S + r) * DH + d;
  float num = pO[o0] * e0 + pO[(long)NH * S * DH + o0] * e1;
  sa[(long)r * DMODEL + col] = num / l;
}

// ---------------- layernorms ----------------
__device__ __forceinline__ float blk_sum(float v, float* red) {
  for (int o = 32; o; o >>= 1) v += __shfl_xor(v, o);
  int tid = threadIdx.x;
  if ((tid & 63) == 0) red[tid >> 6] = v;
  __syncthreads();
  v = red[0] + red[1] + red[2] + red[3];
  __syncthreads();
  return v;
}

__global__ __launch_bounds__(256) void ln1_k(
    const float* __restrict__ src, const float* __restrict__ sa,
    const float* __restrict__ g, const float* __restrict__ be, bf16* __restrict__ y)
{
  __shared__ float red[4];
  const int row = blockIdx.x;
  const int b = row >> 11, s2 = row & 2047;
  const float* xs = src + (long)s2 * (2 * DMODEL) + b * DMODEL;
  const float* ss = sa + (long)s2 * DMODEL;
  const int tid = threadIdx.x;
  float a0 = xs[tid] + ss[tid];
  float a1 = xs[tid + 256] + ss[tid + 256];
  float sum = blk_sum(a0 + a1, red);
  float sq  = blk_sum(a0 * a0 + a1 * a1, red);
  float mu = sum * (1.f / DMODEL);
  float var = sq * (1.f / DMODEL) - mu * mu;
  float rs = rsqrtf(var + LN_EPS);
  y[(long)row * DMODEL + tid]       = (bf16)((a0 - mu) * rs * g[tid] + be[tid]);
  y[(long)row * DMODEL + tid + 256] = (bf16)((a1 - mu) * rs * g[tid + 256] + be[tid + 256]);
}

__global__ __launch_bounds__(256) void ln2_k(
    const bf16* __restrict__ y, const float* __restrict__ ff,
    const float* __restrict__ g, const float* __restrict__ be, float* __restrict__ out)
{
  __shared__ float red[4];
  const int row = blockIdx.x;
  const int b = row >> 11, s2 = row & 2047;
  const int tid = threadIdx.x;
  float a0 = (float)y[(long)row * DMODEL + tid]       + ff[(long)row * DMODEL + tid];
  float a1 = (float)y[(long)row * DMODEL + tid + 256] + ff[(long)row * DMODEL + tid + 256];
  float sum = blk_sum(a0 + a1, red);
  float sq  = blk_sum(a0 * a0 + a1 * a1, red);
  float mu = sum * (1.f / DMODEL);
  float var = sq * (1.f / DMODEL) - mu * mu;
  float rs = rsqrtf(var + LN_EPS);
  float* o = out + (long)s2 * (2 * DMODEL) + b * DMODEL;
  o[tid]       = (a0 - mu) * rs * g[tid] + be[tid];
  o[tid + 256] = (a1 - mu) * rs * g[tid + 256] + be[tid + 256];
}

// ---------------- converts / transposes ----------------
__global__ __launch_bounds__(256) void conv_x0_k(const float* __restrict__ src, bf16* __restrict__ x0b)
{
  long i = (long)blockIdx.x * 256 + threadIdx.x;
  int s2 = (int)(i >> 9), d = (int)(i & 511);
  x0b[i] = (bf16)src[(long)s2 * (2 * DMODEL) + d];
}

__global__ __launch_bounds__(256) void conv_er_k(const float* __restrict__ Er, bf16* __restrict__ erS)
{
  long i = (long)blockIdx.x * 256 + threadIdx.x;
  erS[i] = (bf16)Er[(long)(MAXLEN - S) * DH + i];
}

__global__ void tr_f2b_k(const float* __restrict__ in, bf16* __restrict__ out, int R, int Cn)
{
  __shared__ float t[32][33];
  int c0 = blockIdx.x * 32, r0 = blockIdx.y * 32;
  int tx = threadIdx.x, ty = threadIdx.y;
#pragma unroll
  for (int i = 0; i < 32; i += 8) t[ty + i][tx] = in[(long)(r0 + ty + i) * Cn + c0 + tx];
  __syncthreads();
#pragma unroll
  for (int i = 0; i < 32; i += 8) out[(long)(c0 + ty + i) * R + r0 + tx] = (bf16)t[tx][ty + i];
}

__global__ void tr_b2b_k(const bf16* __restrict__ in, bf16* __restrict__ out, int R, int Cn)
{
  __shared__ bf16 t[32][34];
  int c0 = blockIdx.x * 32, r0 = blockIdx.y * 32;
  int tx = threadIdx.x, ty = threadIdx.y;
#pragma unroll
  for (int i = 0; i < 32; i += 8) t[ty + i][tx] = in[(long)(r0 + ty + i) * Cn + c0 + tx];
  __syncthreads();
#pragma unroll
  for (int i = 0; i < 32; i += 8) out[(long)(c0 + ty + i) * R + r0 + tx] = t[tx][ty + i];
}

// ---------------- host launch ----------------
extern "C" void kernel_launch(void* const* d_in, const int* in_sizes, int n_in,
                              void* d_out, int out_size, void* d_ws, size_t ws_size,
                              hipStream_t stream)
{
  const float* src = (const float*)d_in[0];
  const float* Wq  = (const float*)d_in[1];
  const float* bq  = (const float*)d_in[2];
  const float* Wk  = (const float*)d_in[3];
  const float* bk  = (const float*)d_in[4];
  const float* Wv  = (const float*)d_in[5];
  const float* bv  = (const float*)d_in[6];
  const float* Er  = (const float*)d_in[7];
  const float* W1  = (const float*)d_in[8];
  const float* b1  = (const float*)d_in[9];
  const float* W2  = (const float*)d_in[10];
  const float* b2  = (const float*)d_in[11];
  const float* g1  = (const float*)d_in[12];
  const float* be1 = (const float*)d_in[13];
  const float* g2  = (const float*)d_in[14];
  const float* be2 = (const float*)d_in[15];

  char* wp = (char*)d_ws;
  auto alloc = [&](size_t bytes) { char* p = wp; wp += (bytes + 255) & ~(size_t)255; return p; };

  bf16* x0b = (bf16*)alloc((size_t)S * DMODEL * 2);
  bf16* wqT = (bf16*)alloc((size_t)DMODEL * DMODEL * 2);
  bf16* wkT = (bf16*)alloc((size_t)DMODEL * DMODEL * 2);
  bf16* wvT = (bf16*)alloc((size_t)DMODEL * DMODEL * 2);
  bf16* w1T = (bf16*)alloc((size_t)DFF * DMODEL * 2);
  bf16* w2T = (bf16*)alloc((size_t)DMODEL * DFF * 2);
  bf16* erS = (bf16*)alloc((size_t)S * DH * 2);
  bf16* qb  = (bf16*)alloc((size_t)S * DMODEL * 2);
  bf16* kb  = (bf16*)alloc((size_t)S * DMODEL * 2);
  bf16* vb  = (bf16*)alloc((size_t)S * DMODEL * 2);
  bf16* vt  = (bf16*)alloc((size_t)DMODEL * S * 2);
  bf16* qer = (bf16*)alloc((size_t)NH * S * S * 2);
  float* pO = (float*)alloc((size_t)2 * NH * S * DH * 4);
  float* pM = (float*)alloc((size_t)2 * NH * S * 4);
  float* pL = (float*)alloc((size_t)2 * NH * S * 4);
  float* sa = (float*)alloc((size_t)S * DMODEL * 4);
  bf16* yb  = (bf16*)alloc((size_t)2 * S * DMODEL * 2);
  bf16* h1  = (bf16*)alloc((size_t)2 * S * DFF * 2);
  float* ff = (float*)alloc((size_t)2 * S * DMODEL * 4);

  dim3 tb(32, 8);

  conv_x0_k<<<(S * DMODEL) / 256, 256, 0, stream>>>(src, x0b);
  conv_er_k<<<(S * DH) / 256, 256, 0, stream>>>(Er, erS);
  tr_f2b_k<<<dim3(DMODEL / 32, DMODEL / 32), tb, 0, stream>>>(Wq, wqT, DMODEL, DMODEL);
  tr_f2b_k<<<dim3(DMODEL / 32, DMODEL / 32), tb, 0, stream>>>(Wk, wkT, DMODEL, DMODEL);
  tr_f2b_k<<<dim3(DMODEL / 32, DMODEL / 32), tb, 0, stream>>>(Wv, wvT, DMODEL, DMODEL);
  tr_f2b_k<<<dim3(DFF / 32, DMODEL / 32), tb, 0, stream>>>(W1, w1T, DMODEL, DFF);
  tr_f2b_k<<<dim3(DMODEL / 32, DFF / 32), tb, 0, stream>>>(W2, w2T, DFF, DMODEL);

  // QKV (batch 0 only)
  gemm_k<<<dim3(4, 16, 1), 256, 0, stream>>>(x0b, 0, DMODEL, wqT, 0, DMODEL, qb, 0, DMODEL, bq, 2, S, DMODEL, DMODEL);
  gemm_k<<<dim3(4, 16, 1), 256, 0, stream>>>(x0b, 0, DMODEL, wkT, 0, DMODEL, kb, 0, DMODEL, bk, 2, S, DMODEL, DMODEL);
  gemm_k<<<dim3(4, 16, 1), 256, 0, stream>>>(x0b, 0, DMODEL, wvT, 0, DMODEL, vb, 0, DMODEL, bv, 2, S, DMODEL, DMODEL);

  // V^T
  tr_b2b_k<<<dim3(DMODEL / 32, S / 32), tb, 0, stream>>>(vb, vt, S, DMODEL);

  // QEr[h] = Q_h @ ErS^T
  gemm_k<<<dim3(16, 16, 8), 256, 0, stream>>>(qb, DH, DMODEL, erS, 0, DH, qer, (long)S * S, S, nullptr, 2, S, S, DH);

  // fused attention (scores + skew + softmax + PV), split over column halves
  attn_k<<<dim3(64, NH), 256, 0, stream>>>(qb, kb, vt, qer, pO, pM, pL);
  merge_k<<<(S * DMODEL) / 256, 256, 0, stream>>>(pO, pM, pL, sa);

  // LN1 -> y (bf16)
  ln1_k<<<2 * S, 256, 0, stream>>>(src, sa, g1, be1, yb);

  // FFN
  gemm_k<<<dim3(DFF / 128, (2 * S) / 128, 1), 256, 0, stream>>>(yb, 0, DMODEL, w1T, 0, DMODEL, h1, 0, DFF, b1, 3, 2 * S, DFF, DMODEL);
  gemm_k<<<dim3(DMODEL / 128, (2 * S) / 128, 1), 256, 0, stream>>>(h1, 0, DFF, w2T, 0, DFF, ff, 0, DMODEL, b2, 0, 2 * S, DMODEL, DFF);

  // LN2 -> out
  ln2_k<<<2 * S, 256, 0, stream>>>(yb, ff, g2, be2, (float*)d_out);
}

// Round 3
// 268.180 us; speedup vs baseline: 1.3548x; 1.2180x over previous
//
#include <hip/hip_runtime.h>

typedef __bf16 bf16;
typedef __attribute__((ext_vector_type(8))) __bf16 bf16x8;
typedef __attribute__((ext_vector_type(4))) float f32x4;

#define S 2048
#define DMODEL 512
#define NH 8
#define DH 64
#define DFF 2048
#define MAXLEN 16384
#define LN_EPS 1e-5f
#define LPAD 40
#define NSP 4
#define CW (S / NSP)
#define BC 64

// ---------------- generic bf16 MFMA GEMM: C = A[M,K] @ Bt[N,K]^T (+bias)(+relu) ----------------
// flags: bit0 = relu, bit1 = bf16 output (else fp32)
__global__ __launch_bounds__(256) void gemm_k(
    const bf16* __restrict__ A, long sAz, int lda,
    const bf16* __restrict__ B, long sBz, int ldb,
    void* __restrict__ C, long sCz, int ldc,
    const float* __restrict__ bias, int flags,
    int M, int N, int K)
{
  __shared__ bf16 lsA[128 * LPAD];
  __shared__ bf16 lsB[128 * LPAD];
  const int z = blockIdx.z;
  A += (long)z * sAz;
  B += (long)z * sBz;
  const int m0 = blockIdx.y * 128, n0 = blockIdx.x * 128;
  const int tid = threadIdx.x;
  const int lane = tid & 63, w = tid >> 6;
  const int wr = (w >> 1) * 64, wc = (w & 1) * 64;
  const int r15 = lane & 15, kg = lane >> 4;
  f32x4 acc[4][4] = {};
  for (int k0 = 0; k0 < K; k0 += 32) {
#pragma unroll
    for (int i = 0; i < 2; ++i) {
      int cid = tid + i * 256;
      int row = cid >> 2, kb = (cid & 3) * 8;
      *(bf16x8*)&lsA[row * LPAD + kb] = *(const bf16x8*)&A[(long)(m0 + row) * lda + (k0 + kb)];
      bf16x8 bv = {};
      if (n0 + row < N) bv = *(const bf16x8*)&B[(long)(n0 + row) * ldb + (k0 + kb)];
      *(bf16x8*)&lsB[row * LPAD + kb] = bv;
    }
    __syncthreads();
    bf16x8 af[4], bfr[4];
#pragma unroll
    for (int mi = 0; mi < 4; ++mi) af[mi] = *(const bf16x8*)&lsA[(wr + mi * 16 + r15) * LPAD + kg * 8];
#pragma unroll
    for (int ni = 0; ni < 4; ++ni) bfr[ni] = *(const bf16x8*)&lsB[(wc + ni * 16 + r15) * LPAD + kg * 8];
#pragma unroll
    for (int mi = 0; mi < 4; ++mi)
#pragma unroll
      for (int ni = 0; ni < 4; ++ni)
        acc[mi][ni] = __builtin_amdgcn_mfma_f32_16x16x32_bf16(af[mi], bfr[ni], acc[mi][ni], 0, 0, 0);
    __syncthreads();
  }
#pragma unroll
  for (int mi = 0; mi < 4; ++mi)
#pragma unroll
    for (int ni = 0; ni < 4; ++ni) {
      int col = n0 + wc + ni * 16 + r15;
      if (col >= N) continue;
      float bv = bias ? bias[col] : 0.f;
#pragma unroll
      for (int r = 0; r < 4; ++r) {
        int row = m0 + wr + mi * 16 + kg * 4 + r;
        float v = acc[mi][ni][r] + bv;
        if (flags & 1) v = fmaxf(v, 0.f);
        if (flags & 2) ((bf16*)C)[(long)z * sCz + (long)row * ldc + col] = (bf16)v;
        else           ((float*)C)[(long)z * sCz + (long)row * ldc + col] = v;
      }
    }
}

// ---------------- fused attention v2 ----------------
// grid (32*NSP, NH): rb = bx>>2 (64-row block), sp = bx&3 (column quarter of 512)
// LDS 28KB: K tile (reused as P region after QK), V^T tile, qer band.
__global__ __launch_bounds__(256, 4) void attn_k(
    const bf16* __restrict__ qg, const bf16* __restrict__ kgl, const bf16* __restrict__ vtg,
    const bf16* __restrict__ qer,
    float* __restrict__ pO, float* __restrict__ pM, float* __restrict__ pL)
{
  __shared__ bf16 KP[64 * 72];    // K tile [c][k], reused as P[w][16][72]
  __shared__ bf16 Vl[64 * 72];    // V^T tile [d][c]
  __shared__ bf16 Band[64 * 80];  // qer band per row (16B-aligned strips)
  const int bx = blockIdx.x, h = blockIdx.y;
  const int rb = bx >> 2, sp = bx & 3;
  const int r0 = rb * 64;
  const int cb = sp * CW;
  const int tid = threadIdx.x, lane = tid & 63, w = tid >> 6;
  const int r15 = lane & 15, g = lane >> 4;
  const long hb = (long)h * S * S;
  const float CST = 0.18033688f; // (1/8) * log2(e)

  // persistent Q A-frags (row = r0+16w+r15, k = g*8..)
  bf16x8 qf0, qf1;
  {
    const bf16* qrow = qg + (long)(r0 + w * 16 + r15) * DMODEL + h * DH;
    qf0 = *(const bf16x8*)&qrow[g * 8];
    qf1 = *(const bf16x8*)&qrow[32 + g * 8];
  }
  f32x4 Oacc[4] = {};
  float m2[4], l2[4];
#pragma unroll
  for (int r = 0; r < 4; ++r) { m2[r] = -1e30f; l2[r] = 0.f; }

  const int rw = w * 16 + 4 * g;  // block-local row for reg r: rw + r
  const int rGlob = r0 + rw;
  const int kRow = tid >> 3, kCh = (tid & 7) * 8;

  for (int t = 0; t < CW / BC; ++t) {
    const int c0 = cb + t * BC;
    __syncthreads();
    // stage K tile [64][64] (pad-72 rows)
    *(bf16x8*)&KP[kRow * 72 + kCh]        = *(const bf16x8*)&kgl[(long)(c0 + kRow) * DMODEL + h * DH + kCh];
    *(bf16x8*)&KP[(kRow + 32) * 72 + kCh] = *(const bf16x8*)&kgl[(long)(c0 + kRow + 32) * DMODEL + h * DH + kCh];
    // stage V^T tile [64][64]
    *(bf16x8*)&Vl[kRow * 72 + kCh]        = *(const bf16x8*)&vtg[(long)(h * DH + kRow) * S + c0 + kCh];
    *(bf16x8*)&Vl[(kRow + 32) * 72 + kCh] = *(const bf16x8*)&vtg[(long)(h * DH + kRow + 32) * S + c0 + kCh];
    // stage qer band: row `row` covers flat qer[rg*S + a .. a+80), a = (c0+S-2-rg) & ~7
#pragma unroll
    for (int i = 0; i < 3; ++i) {
      int idx = tid + i * 256;
      if (i < 2 || tid < 128) {
        int row = idx / 10, ch = idx - row * 10;
        int rg = r0 + row;
        int a = (c0 + S - 2 - rg) & ~7;
        *(bf16x8*)&Band[row * 80 + ch * 8] = *(const bf16x8*)&qer[hb + (long)rg * S + a + ch * 8];
      }
    }
    __syncthreads();

    // QK^T
    f32x4 sc[4];
    __builtin_amdgcn_s_setprio(1);
#pragma unroll
    for (int ni = 0; ni < 4; ++ni) {
      bf16x8 b0 = *(const bf16x8*)&KP[(ni * 16 + r15) * 72 + g * 8];
      bf16x8 b1 = *(const bf16x8*)&KP[(ni * 16 + r15) * 72 + 32 + g * 8];
      f32x4 a = {};
      a = __builtin_amdgcn_mfma_f32_16x16x32_bf16(qf0, b0, a, 0, 0, 0);
      a = __builtin_amdgcn_mfma_f32_16x16x32_bf16(qf1, b1, a, 0, 0, 0);
      sc[ni] = a;
    }
    __builtin_amdgcn_s_setprio(0);

    // srel (branchless skew from LDS band) + scale into log2 domain
#pragma unroll
    for (int r = 0; r < 4; ++r) {
      const int rg = rGlob + r;
      const int boff = (c0 + S - 2 - rg) & 7;
      const int rowb = (rw + r) * 80;
#pragma unroll
      for (int ni = 0; ni < 4; ++ni) {
        int cl = ni * 16 + r15;          // cg - c0
        int cg = c0 + cl;
        int le = (cg <= rg) ? 1 : 0;
        float srel = (cg == rg + 1) ? 0.f : (float)Band[rowb + boff + cl + le];
        sc[ni][r] = (sc[ni][r] + srel) * CST;
      }
    }

    // online softmax (base-2)
    float tmax[4];
#pragma unroll
    for (int r = 0; r < 4; ++r)
      tmax[r] = fmaxf(fmaxf(sc[0][r], sc[1][r]), fmaxf(sc[2][r], sc[3][r]));
#pragma unroll
    for (int o = 1; o < 16; o <<= 1)
#pragma unroll
      for (int r = 0; r < 4; ++r) tmax[r] = fmaxf(tmax[r], __shfl_xor(tmax[r], o));

    float al[4], tsum[4];
#pragma unroll
    for (int r = 0; r < 4; ++r) {
      float mn = fmaxf(m2[r], tmax[r]);
      al[r] = exp2f(m2[r] - mn);
      m2[r] = mn;
      tsum[r] = 0.f;
    }
#pragma unroll
    for (int ni = 0; ni < 4; ++ni)
#pragma unroll
      for (int r = 0; r < 4; ++r) {
        float p = exp2f(sc[ni][r] - m2[r]);
        sc[ni][r] = p;
        tsum[r] += p;
      }
#pragma unroll
    for (int o = 1; o < 16; o <<= 1)
#pragma unroll
      for (int r = 0; r < 4; ++r) tsum[r] += __shfl_xor(tsum[r], o);
#pragma unroll
    for (int r = 0; r < 4; ++r) l2[r] = l2[r] * al[r] + tsum[r];
#pragma unroll
    for (int no = 0; no < 4; ++no)
#pragma unroll
      for (int r = 0; r < 4; ++r) Oacc[no][r] *= al[r];

    __syncthreads(); // all waves done reading K tile -> safe to overwrite with P

    // write P into KP region (own wave slice), then PV
    bf16* Pw = &KP[w * 16 * 72];
#pragma unroll
    for (int ni = 0; ni < 4; ++ni)
#pragma unroll
      for (int r = 0; r < 4; ++r)
        Pw[(4 * g + r) * 72 + ni * 16 + r15] = (bf16)sc[ni][r];

    __builtin_amdgcn_s_setprio(1);
#pragma unroll
    for (int kc = 0; kc < 2; ++kc) {
      bf16x8 af = *(const bf16x8*)&Pw[r15 * 72 + kc * 32 + g * 8];
#pragma unroll
      for (int no = 0; no < 4; ++no) {
        bf16x8 bv = *(const bf16x8*)&Vl[(no * 16 + r15) * 72 + kc * 32 + g * 8];
        Oacc[no] = __builtin_amdgcn_mfma_f32_16x16x32_bf16(af, bv, Oacc[no], 0, 0, 0);
      }
    }
    __builtin_amdgcn_s_setprio(0);
  }

  // write partials
  const long ob = ((long)sp * NH + h) * S * DH;
#pragma unroll
  for (int no = 0; no < 4; ++no)
#pragma unroll
    for (int r = 0; r < 4; ++r)
      pO[ob + (long)(rGlob + r) * DH + no * 16 + r15] = Oacc[no][r];
  if (r15 == 0) {
    const long sb = ((long)sp * NH + h) * S;
#pragma unroll
    for (int r = 0; r < 4; ++r) {
      pM[sb + rGlob + r] = m2[r];
      pL[sb + rGlob + r] = l2[r];
    }
  }
}

// ---------------- merge the NSP column-quarter partials -> sa[r][DMODEL] (f32) ----------------
__global__ __launch_bounds__(256) void merge_k(
    const float* __restrict__ pO, const float* __restrict__ pM, const float* __restrict__ pL,
    float* __restrict__ sa)
{
  int i = blockIdx.x * 256 + threadIdx.x;
  int r = i >> 9, col = i & 511;
  int h = col >> 6, d = col & 63;
  long i0 = (long)h * S + r;
  float mm = -1e30f;
  float ms[NSP];
#pragma unroll
  for (int s = 0; s < NSP; ++s) { ms[s] = pM[(long)s * NH * S + i0]; mm = fmaxf(mm, ms[s]); }
  float num = 0.f, den = 0.f;
#pragma unroll
  for (int s = 0; s < NSP; ++s) {
    float e = exp2f(ms[s] - mm);
    den += pL[(long)s * NH * S + i0] * e;
    num += pO[(long)s * NH * S * DH + i0 * DH + d] * e;
  }
  sa[(long)r * DMODEL + col] = num / den;
}

// ---------------- layernorms ----------------
__device__ __forceinline__ float blk_sum(float v, float* red) {
  for (int o = 32; o; o >>= 1) v += __shfl_xor(v, o);
  int tid = threadIdx.x;
  if ((tid & 63) == 0) red[tid >> 6] = v;
  __syncthreads();
  v = red[0] + red[1] + red[2] + red[3];
  __syncthreads();
  return v;
}

__global__ __launch_bounds__(256) void ln1_k(
    const float* __restrict__ src, const float* __restrict__ sa,
    const float* __restrict__ g, const float* __restrict__ be, bf16* __restrict__ y)
{
  __shared__ float red[4];
  const int row = blockIdx.x;
  const int b = row >> 11, s2 = row & 2047;
  const float* xs = src + (long)s2 * (2 * DMODEL) + b * DMODEL;
  const float* ss = sa + (long)s2 * DMODEL;
  const int tid = threadIdx.x;
  float a0 = xs[tid] + ss[tid];
  float a1 = xs[tid + 256] + ss[tid + 256];
  float sum = blk_sum(a0 + a1, red);
  float sq  = blk_sum(a0 * a0 + a1 * a1, red);
  float mu = sum * (1.f / DMODEL);
  float var = sq * (1.f / DMODEL) - mu * mu;
  float rs = rsqrtf(var + LN_EPS);
  y[(long)row * DMODEL + tid]       = (bf16)((a0 - mu) * rs * g[tid] + be[tid]);
  y[(long)row * DMODEL + tid + 256] = (bf16)((a1 - mu) * rs * g[tid + 256] + be[tid + 256]);
}

__global__ __launch_bounds__(256) void ln2_k(
    const bf16* __restrict__ y, const float* __restrict__ ff,
    const float* __restrict__ g, const float* __restrict__ be, float* __restrict__ out)
{
  __shared__ float red[4];
  const int row = blockIdx.x;
  const int b = row >> 11, s2 = row & 2047;
  const int tid = threadIdx.x;
  float a0 = (float)y[(long)row * DMODEL + tid]       + ff[(long)row * DMODEL + tid];
  float a1 = (float)y[(long)row * DMODEL + tid + 256] + ff[(long)row * DMODEL + tid + 256];
  float sum = blk_sum(a0 + a1, red);
  float sq  = blk_sum(a0 * a0 + a1 * a1, red);
  float mu = sum * (1.f / DMODEL);
  float var = sq * (1.f / DMODEL) - mu * mu;
  float rs = rsqrtf(var + LN_EPS);
  float* o = out + (long)s2 * (2 * DMODEL) + b * DMODEL;
  o[tid]       = (a0 - mu) * rs * g[tid] + be[tid];
  o[tid + 256] = (a1 - mu) * rs * g[tid + 256] + be[tid + 256];
}

// ---------------- converts / transposes ----------------
__global__ __launch_bounds__(256) void conv_x0_k(const float* __restrict__ src, bf16* __restrict__ x0b)
{
  long i = (long)blockIdx.x * 256 + threadIdx.x;
  int s2 = (int)(i >> 9), d = (int)(i & 511);
  x0b[i] = (bf16)src[(long)s2 * (2 * DMODEL) + d];
}

__global__ __launch_bounds__(256) void conv_er_k(const float* __restrict__ Er, bf16* __restrict__ erS)
{
  long i = (long)blockIdx.x * 256 + threadIdx.x;
  erS[i] = (bf16)Er[(long)(MAXLEN - S) * DH + i];
}

__global__ void tr_f2b_k(const float* __restrict__ in, bf16* __restrict__ out, int R, int Cn)
{
  __shared__ float t[32][33];
  int c0 = blockIdx.x * 32, r0 = blockIdx.y * 32;
  int tx = threadIdx.x, ty = threadIdx.y;
#pragma unroll
  for (int i = 0; i < 32; i += 8) t[ty + i][tx] = in[(long)(r0 + ty + i) * Cn + c0 + tx];
  __syncthreads();
#pragma unroll
  for (int i = 0; i < 32; i += 8) out[(long)(c0 + ty + i) * R + r0 + tx] = (bf16)t[tx][ty + i];
}

__global__ void tr_b2b_k(const bf16* __restrict__ in, bf16* __restrict__ out, int R, int Cn)
{
  __shared__ bf16 t[32][34];
  int c0 = blockIdx.x * 32, r0 = blockIdx.y * 32;
  int tx = threadIdx.x, ty = threadIdx.y;
#pragma unroll
  for (int i = 0; i < 32; i += 8) t[ty + i][tx] = in[(long)(r0 + ty + i) * Cn + c0 + tx];
  __syncthreads();
#pragma unroll
  for (int i = 0; i < 32; i += 8) out[(long)(c0 + ty + i) * R + r0 + tx] = t[tx][ty + i];
}

// ---------------- host launch ----------------
extern "C" void kernel_launch(void* const* d_in, const int* in_sizes, int n_in,
                              void* d_out, int out_size, void* d_ws, size_t ws_size,
                              hipStream_t stream)
{
  const float* src = (const float*)d_in[0];
  const float* Wq  = (const float*)d_in[1];
  const float* bq  = (const float*)d_in[2];
  const float* Wk  = (const float*)d_in[3];
  const float* bk  = (const float*)d_in[4];
  const float* Wv  = (const float*)d_in[5];
  const float* bv  = (const float*)d_in[6];
  const float* Er  = (const float*)d_in[7];
  const float* W1  = (const float*)d_in[8];
  const float* b1  = (const float*)d_in[9];
  const float* W2  = (const float*)d_in[10];
  const float* b2  = (const float*)d_in[11];
  const float* g1  = (const float*)d_in[12];
  const float* be1 = (const float*)d_in[13];
  const float* g2  = (const float*)d_in[14];
  const float* be2 = (const float*)d_in[15];

  char* wp = (char*)d_ws;
  auto alloc = [&](size_t bytes) { char* p = wp; wp += (bytes + 255) & ~(size_t)255; return p; };

  bf16* x0b = (bf16*)alloc((size_t)S * DMODEL * 2);
  bf16* wqT = (bf16*)alloc((size_t)DMODEL * DMODEL * 2);
  bf16* wkT = (bf16*)alloc((size_t)DMODEL * DMODEL * 2);
  bf16* wvT = (bf16*)alloc((size_t)DMODEL * DMODEL * 2);
  bf16* w1T = (bf16*)alloc((size_t)DFF * DMODEL * 2);
  bf16* w2T = (bf16*)alloc((size_t)DMODEL * DFF * 2);
  bf16* erS = (bf16*)alloc((size_t)S * DH * 2);
  bf16* qb  = (bf16*)alloc((size_t)S * DMODEL * 2);
  bf16* kb  = (bf16*)alloc((size_t)S * DMODEL * 2);
  bf16* vb  = (bf16*)alloc((size_t)S * DMODEL * 2);
  bf16* vt  = (bf16*)alloc((size_t)DMODEL * S * 2);
  bf16* qer = (bf16*)alloc((size_t)NH * S * S * 2);
  float* pO = (float*)alloc((size_t)NSP * NH * S * DH * 4);
  float* pM = (float*)alloc((size_t)NSP * NH * S * 4);
  float* pL = (float*)alloc((size_t)NSP * NH * S * 4);
  float* sa = (float*)alloc((size_t)S * DMODEL * 4);
  bf16* yb  = (bf16*)alloc((size_t)2 * S * DMODEL * 2);
  bf16* h1  = (bf16*)alloc((size_t)2 * S * DFF * 2);
  float* ff = (float*)alloc((size_t)2 * S * DMODEL * 4);

  dim3 tb(32, 8);

  conv_x0_k<<<(S * DMODEL) / 256, 256, 0, stream>>>(src, x0b);
  conv_er_k<<<(S * DH) / 256, 256, 0, stream>>>(Er, erS);
  tr_f2b_k<<<dim3(DMODEL / 32, DMODEL / 32), tb, 0, stream>>>(Wq, wqT, DMODEL, DMODEL);
  tr_f2b_k<<<dim3(DMODEL / 32, DMODEL / 32), tb, 0, stream>>>(Wk, wkT, DMODEL, DMODEL);
  tr_f2b_k<<<dim3(DMODEL / 32, DMODEL / 32), tb, 0, stream>>>(Wv, wvT, DMODEL, DMODEL);
  tr_f2b_k<<<dim3(DFF / 32, DMODEL / 32), tb, 0, stream>>>(W1, w1T, DMODEL, DFF);
  tr_f2b_k<<<dim3(DMODEL / 32, DFF / 32), tb, 0, stream>>>(W2, w2T, DFF, DMODEL);

  // QKV (batch 0 only)
  gemm_k<<<dim3(4, 16, 1), 256, 0, stream>>>(x0b, 0, DMODEL, wqT, 0, DMODEL, qb, 0, DMODEL, bq, 2, S, DMODEL, DMODEL);
  gemm_k<<<dim3(4, 16, 1), 256, 0, stream>>>(x0b, 0, DMODEL, wkT, 0, DMODEL, kb, 0, DMODEL, bk, 2, S, DMODEL, DMODEL);
  gemm_k<<<dim3(4, 16, 1), 256, 0, stream>>>(x0b, 0, DMODEL, wvT, 0, DMODEL, vb, 0, DMODEL, bv, 2, S, DMODEL, DMODEL);

  // V^T
  tr_b2b_k<<<dim3(DMODEL / 32, S / 32), tb, 0, stream>>>(vb, vt, S, DMODEL);

  // QEr[h] = Q_h @ ErS^T
  gemm_k<<<dim3(16, 16, 8), 256, 0, stream>>>(qb, DH, DMODEL, erS, 0, DH, qer, (long)S * S, S, nullptr, 2, S, S, DH);

  // fused attention (scores + skew + softmax + PV), split over column quarters
  attn_k<<<dim3(32 * NSP, NH), 256, 0, stream>>>(qb, kb, vt, qer, pO, pM, pL);
  merge_k<<<(S * DMODEL) / 256, 256, 0, stream>>>(pO, pM, pL, sa);

  // LN1 -> y (bf16)
  ln1_k<<<2 * S, 256, 0, stream>>>(src, sa, g1, be1, yb);

  // FFN
  gemm_k<<<dim3(DFF / 128, (2 * S) / 128, 1), 256, 0, stream>>>(yb, 0, DMODEL, w1T, 0, DMODEL, h1, 0, DFF, b1, 3, 2 * S, DFF, DMODEL);
  gemm_k<<<dim3(DMODEL / 128, (2 * S) / 128, 1), 256, 0, stream>>>(h1, 0, DFF, w2T, 0, DFF, ff, 0, DMODEL, b2, 0, 2 * S, DMODEL, DFF);

  // LN2 -> out
  ln2_k<<<2 * S, 256, 0, stream>>>(yb, ff, g2, be2, (float*)d_out);
}

// Round 4
// 176.802 us; speedup vs baseline: 2.0550x; 1.5168x over previous
//
#include <hip/hip_runtime.h>

typedef __bf16 bf16;
typedef __attribute__((ext_vector_type(8))) __bf16 bf16x8;
typedef __attribute__((ext_vector_type(4))) float f32x4;

#define S 2048
#define DMODEL 512
#define NH 8
#define DH 64
#define DFF 2048
#define MAXLEN 16384
#define LN_EPS 1e-5f
#define NSP 4
#define CW (S / NSP)
#define BC 64

__device__ __forceinline__ void gload16(const bf16* g, bf16* l) {
  __builtin_amdgcn_global_load_lds(
      (const __attribute__((address_space(1))) void*)g,
      (__attribute__((address_space(3))) void*)l, 16, 0, 0);
}

// ---------------- m97-style bf16 MFMA GEMM: C = A[M,K] @ Bt[N,K]^T (+bias)(+relu) ----------------
// flags: bit0 = relu, bit1 = bf16 output (else fp32)
// z-dim: batch via sAz/sBz/sCz element strides (also used for split-K by striding into K).
__global__ __launch_bounds__(256) void gemm_k(
    const bf16* __restrict__ A, long sAz, int lda,
    const bf16* __restrict__ B, long sBz, int ldb,
    void* __restrict__ C, long sCz, int ldc,
    const float* __restrict__ bias, long sBiasZ, int flags,
    int M, int N, int K)
{
  __shared__ bf16 lsA[128 * 32];
  __shared__ bf16 lsB[128 * 32];
  const int z = blockIdx.z;
  A += (long)z * sAz;
  B += (long)z * sBz;
  const int m0 = blockIdx.y * 128, n0 = blockIdx.x * 128;
  const int tid = threadIdx.x;
  const int lane = tid & 63, w = tid >> 6;
  const int wr = (w >> 1) * 64, wc = (w & 1) * 64;
  const int r15 = lane & 15, kg = lane >> 4;
  const int srow = lane >> 2, scol = (lane & 3) * 8;

  const bf16* Ag0 = A + (long)(m0 + 32 * w + srow) * lda + scol;
  const bf16* Ag1 = Ag0 + 16 * lda;
  const bf16* Bg0 = B + (long)(n0 + 32 * w + srow) * ldb + scol;
  const bf16* Bg1 = Bg0 + 16 * ldb;
  bf16* La0 = &lsA[(32 * w + srow) * 32 + scol];
  bf16* La1 = La0 + 16 * 32;
  bf16* Lb0 = &lsB[(32 * w + srow) * 32 + scol];
  bf16* Lb1 = Lb0 + 16 * 32;

  f32x4 acc[4][4] = {};
  for (int k0 = 0; k0 < K; k0 += 32) {
    gload16(Ag0 + k0, La0);
    gload16(Ag1 + k0, La1);
    gload16(Bg0 + k0, Lb0);
    gload16(Bg1 + k0, Lb1);
    __syncthreads();
    bf16x8 af[4], bfr[4];
#pragma unroll
    for (int mi = 0; mi < 4; ++mi) af[mi] = *(const bf16x8*)&lsA[(wr + mi * 16 + r15) * 32 + kg * 8];
#pragma unroll
    for (int ni = 0; ni < 4; ++ni) bfr[ni] = *(const bf16x8*)&lsB[(wc + ni * 16 + r15) * 32 + kg * 8];
    __builtin_amdgcn_s_setprio(1);
#pragma unroll
    for (int mi = 0; mi < 4; ++mi)
#pragma unroll
      for (int ni = 0; ni < 4; ++ni)
        acc[mi][ni] = __builtin_amdgcn_mfma_f32_16x16x32_bf16(af[mi], bfr[ni], acc[mi][ni], 0, 0, 0);
    __builtin_amdgcn_s_setprio(0);
    __syncthreads();
  }
  const float* bz = bias ? bias + (long)z * sBiasZ : nullptr;
#pragma unroll
  for (int mi = 0; mi < 4; ++mi)
#pragma unroll
    for (int ni = 0; ni < 4; ++ni) {
      int col = n0 + wc + ni * 16 + r15;
      float bv = bz ? bz[col] : 0.f;
#pragma unroll
      for (int r = 0; r < 4; ++r) {
        int row = m0 + wr + mi * 16 + kg * 4 + r;
        float v = acc[mi][ni][r] + bv;
        if (flags & 1) v = fmaxf(v, 0.f);
        if (flags & 2) ((bf16*)C)[(long)z * sCz + (long)row * ldc + col] = (bf16)v;
        else           ((float*)C)[(long)z * sCz + (long)row * ldc + col] = v;
      }
    }
}

// ---------------- fused attention (unchanged from r3) ----------------
__global__ __launch_bounds__(256, 4) void attn_k(
    const bf16* __restrict__ qg, const bf16* __restrict__ kgl, const bf16* __restrict__ vtg,
    const bf16* __restrict__ qer,
    float* __restrict__ pO, float* __restrict__ pM, float* __restrict__ pL)
{
  __shared__ bf16 KP[64 * 72];
  __shared__ bf16 Vl[64 * 72];
  __shared__ bf16 Band[64 * 80];
  const int bx = blockIdx.x, h = blockIdx.y;
  const int rb = bx >> 2, sp = bx & 3;
  const int r0 = rb * 64;
  const int cb = sp * CW;
  const int tid = threadIdx.x, lane = tid & 63, w = tid >> 6;
  const int r15 = lane & 15, g = lane >> 4;
  const long hb = (long)h * S * S;
  const float CST = 0.18033688f; // (1/8) * log2(e)

  bf16x8 qf0, qf1;
  {
    const bf16* qrow = qg + (long)(r0 + w * 16 + r15) * DMODEL + h * DH;
    qf0 = *(const bf16x8*)&qrow[g * 8];
    qf1 = *(const bf16x8*)&qrow[32 + g * 8];
  }
  f32x4 Oacc[4] = {};
  float m2[4], l2[4];
#pragma unroll
  for (int r = 0; r < 4; ++r) { m2[r] = -1e30f; l2[r] = 0.f; }

  const int rw = w * 16 + 4 * g;
  const int rGlob = r0 + rw;
  const int kRow = tid >> 3, kCh = (tid & 7) * 8;

  for (int t = 0; t < CW / BC; ++t) {
    const int c0 = cb + t * BC;
    __syncthreads();
    *(bf16x8*)&KP[kRow * 72 + kCh]        = *(const bf16x8*)&kgl[(long)(c0 + kRow) * DMODEL + h * DH + kCh];
    *(bf16x8*)&KP[(kRow + 32) * 72 + kCh] = *(const bf16x8*)&kgl[(long)(c0 + kRow + 32) * DMODEL + h * DH + kCh];
    *(bf16x8*)&Vl[kRow * 72 + kCh]        = *(const bf16x8*)&vtg[(long)(h * DH + kRow) * S + c0 + kCh];
    *(bf16x8*)&Vl[(kRow + 32) * 72 + kCh] = *(const bf16x8*)&vtg[(long)(h * DH + kRow + 32) * S + c0 + kCh];
#pragma unroll
    for (int i = 0; i < 3; ++i) {
      int idx = tid + i * 256;
      if (i < 2 || tid < 128) {
        int row = idx / 10, ch = idx - row * 10;
        int rg = r0 + row;
        int a = (c0 + S - 2 - rg) & ~7;
        *(bf16x8*)&Band[row * 80 + ch * 8] = *(const bf16x8*)&qer[hb + (long)rg * S + a + ch * 8];
      }
    }
    __syncthreads();

    f32x4 sc[4];
    __builtin_amdgcn_s_setprio(1);
#pragma unroll
    for (int ni = 0; ni < 4; ++ni) {
      bf16x8 b0 = *(const bf16x8*)&KP[(ni * 16 + r15) * 72 + g * 8];
      bf16x8 b1 = *(const bf16x8*)&KP[(ni * 16 + r15) * 72 + 32 + g * 8];
      f32x4 a = {};
      a = __builtin_amdgcn_mfma_f32_16x16x32_bf16(qf0, b0, a, 0, 0, 0);
      a = __builtin_amdgcn_mfma_f32_16x16x32_bf16(qf1, b1, a, 0, 0, 0);
      sc[ni] = a;
    }
    __builtin_amdgcn_s_setprio(0);

#pragma unroll
    for (int r = 0; r < 4; ++r) {
      const int rg = rGlob + r;
      const int boff = (c0 + S - 2 - rg) & 7;
      const int rowb = (rw + r) * 80;
#pragma unroll
      for (int ni = 0; ni < 4; ++ni) {
        int cl = ni * 16 + r15;
        int cg = c0 + cl;
        int le = (cg <= rg) ? 1 : 0;
        float srel = (cg == rg + 1) ? 0.f : (float)Band[rowb + boff + cl + le];
        sc[ni][r] = (sc[ni][r] + srel) * CST;
      }
    }

    float tmax[4];
#pragma unroll
    for (int r = 0; r < 4; ++r)
      tmax[r] = fmaxf(fmaxf(sc[0][r], sc[1][r]), fmaxf(sc[2][r], sc[3][r]));
#pragma unroll
    for (int o = 1; o < 16; o <<= 1)
#pragma unroll
      for (int r = 0; r < 4; ++r) tmax[r] = fmaxf(tmax[r], __shfl_xor(tmax[r], o));

    float al[4], tsum[4];
#pragma unroll
    for (int r = 0; r < 4; ++r) {
      float mn = fmaxf(m2[r], tmax[r]);
      al[r] = exp2f(m2[r] - mn);
      m2[r] = mn;
      tsum[r] = 0.f;
    }
#pragma unroll
    for (int ni = 0; ni < 4; ++ni)
#pragma unroll
      for (int r = 0; r < 4; ++r) {
        float p = exp2f(sc[ni][r] - m2[r]);
        sc[ni][r] = p;
        tsum[r] += p;
      }
#pragma unroll
    for (int o = 1; o < 16; o <<= 1)
#pragma unroll
      for (int r = 0; r < 4; ++r) tsum[r] += __shfl_xor(tsum[r], o);
#pragma unroll
    for (int r = 0; r < 4; ++r) l2[r] = l2[r] * al[r] + tsum[r];
#pragma unroll
    for (int no = 0; no < 4; ++no)
#pragma unroll
      for (int r = 0; r < 4; ++r) Oacc[no][r] *= al[r];

    __syncthreads();

    bf16* Pw = &KP[w * 16 * 72];
#pragma unroll
    for (int ni = 0; ni < 4; ++ni)
#pragma unroll
      for (int r = 0; r < 4; ++r)
        Pw[(4 * g + r) * 72 + ni * 16 + r15] = (bf16)sc[ni][r];

    __builtin_amdgcn_s_setprio(1);
#pragma unroll
    for (int kc = 0; kc < 2; ++kc) {
      bf16x8 af = *(const bf16x8*)&Pw[r15 * 72 + kc * 32 + g * 8];
#pragma unroll
      for (int no = 0; no < 4; ++no) {
        bf16x8 bv = *(const bf16x8*)&Vl[(no * 16 + r15) * 72 + kc * 32 + g * 8];
        Oacc[no] = __builtin_amdgcn_mfma_f32_16x16x32_bf16(af, bv, Oacc[no], 0, 0, 0);
      }
    }
    __builtin_amdgcn_s_setprio(0);
  }

  const long ob = ((long)sp * NH + h) * S * DH;
#pragma unroll
  for (int no = 0; no < 4; ++no)
#pragma unroll
    for (int r = 0; r < 4; ++r)
      pO[ob + (long)(rGlob + r) * DH + no * 16 + r15] = Oacc[no][r];
  if (r15 == 0) {
    const long sb = ((long)sp * NH + h) * S;
#pragma unroll
    for (int r = 0; r < 4; ++r) {
      pM[sb + rGlob + r] = m2[r];
      pL[sb + rGlob + r] = l2[r];
    }
  }
}

// ---------------- merge the NSP column-quarter partials -> sa[r][DMODEL] (f32) ----------------
__global__ __launch_bounds__(256) void merge_k(
    const float* __restrict__ pO, const float* __restrict__ pM, const float* __restrict__ pL,
    float* __restrict__ sa)
{
  int i = blockIdx.x * 256 + threadIdx.x;
  int r = i >> 9, col = i & 511;
  int h = col >> 6, d = col & 63;
  long i0 = (long)h * S + r;
  float mm = -1e30f;
  float ms[NSP];
#pragma unroll
  for (int s = 0; s < NSP; ++s) { ms[s] = pM[(long)s * NH * S + i0]; mm = fmaxf(mm, ms[s]); }
  float num = 0.f, den = 0.f;
#pragma unroll
  for (int s = 0; s < NSP; ++s) {
    float e = exp2f(ms[s] - mm);
    den += pL[(long)s * NH * S + i0] * e;
    num += pO[(long)s * NH * S * DH + i0 * DH + d] * e;
  }
  sa[(long)r * DMODEL + col] = num / den;
}

// ---------------- layernorms ----------------
__device__ __forceinline__ float blk_sum(float v, float* red) {
  for (int o = 32; o; o >>= 1) v += __shfl_xor(v, o);
  int tid = threadIdx.x;
  if ((tid & 63) == 0) red[tid >> 6] = v;
  __syncthreads();
  v = red[0] + red[1] + red[2] + red[3];
  __syncthreads();
  return v;
}

__global__ __launch_bounds__(256) void ln1_k(
    const float* __restrict__ src, const float* __restrict__ sa,
    const float* __restrict__ g, const float* __restrict__ be, bf16* __restrict__ y)
{
  __shared__ float red[4];
  const int row = blockIdx.x;
  const int b = row >> 11, s2 = row & 2047;
  const float* xs = src + (long)s2 * (2 * DMODEL) + b * DMODEL;
  const float* ss = sa + (long)s2 * DMODEL;
  const int tid = threadIdx.x;
  float a0 = xs[tid] + ss[tid];
  float a1 = xs[tid + 256] + ss[tid + 256];
  float sum = blk_sum(a0 + a1, red);
  float sq  = blk_sum(a0 * a0 + a1 * a1, red);
  float mu = sum * (1.f / DMODEL);
  float var = sq * (1.f / DMODEL) - mu * mu;
  float rs = rsqrtf(var + LN_EPS);
  y[(long)row * DMODEL + tid]       = (bf16)((a0 - mu) * rs * g[tid] + be[tid]);
  y[(long)row * DMODEL + tid + 256] = (bf16)((a1 - mu) * rs * g[tid + 256] + be[tid + 256]);
}

// out = LN( y + sum_4(pFF) + b2 ) ; pFF are split-K partials
__global__ __launch_bounds__(256) void ln2_k(
    const bf16* __restrict__ y, const float* __restrict__ pFF, long pStride,
    const float* __restrict__ b2,
    const float* __restrict__ g, const float* __restrict__ be, float* __restrict__ out)
{
  __shared__ float red[4];
  const int row = blockIdx.x;
  const int b = row >> 11, s2 = row & 2047;
  const int tid = threadIdx.x;
  long i0 = (long)row * DMODEL + tid;
  long i1 = i0 + 256;
  float f0 = pFF[i0] + pFF[i0 + pStride] + pFF[i0 + 2 * pStride] + pFF[i0 + 3 * pStride] + b2[tid];
  float f1 = pFF[i1] + pFF[i1 + pStride] + pFF[i1 + 2 * pStride] + pFF[i1 + 3 * pStride] + b2[tid + 256];
  float a0 = (float)y[i0] + f0;
  float a1 = (float)y[i1] + f1;
  float sum = blk_sum(a0 + a1, red);
  float sq  = blk_sum(a0 * a0 + a1 * a1, red);
  float mu = sum * (1.f / DMODEL);
  float var = sq * (1.f / DMODEL) - mu * mu;
  float rs = rsqrtf(var + LN_EPS);
  float* o = out + (long)s2 * (2 * DMODEL) + b * DMODEL;
  o[tid]       = (a0 - mu) * rs * g[tid] + be[tid];
  o[tid + 256] = (a1 - mu) * rs * g[tid + 256] + be[tid + 256];
}

// ---------------- converts / transposes ----------------
__global__ __launch_bounds__(256) void conv_x0_k(const float* __restrict__ src, bf16* __restrict__ x0b)
{
  long i = (long)blockIdx.x * 256 + threadIdx.x;
  int s2 = (int)(i >> 9), d = (int)(i & 511);
  x0b[i] = (bf16)src[(long)s2 * (2 * DMODEL) + d];
}

__global__ __launch_bounds__(256) void conv_er_k(const float* __restrict__ Er, bf16* __restrict__ erS)
{
  long i = (long)blockIdx.x * 256 + threadIdx.x;
  erS[i] = (bf16)Er[(long)(MAXLEN - S) * DH + i];
}

__global__ __launch_bounds__(256) void pack_bias_k(
    const float* __restrict__ a, const float* __restrict__ b, const float* __restrict__ c,
    float* __restrict__ o)
{
  int t = blockIdx.x * 256 + threadIdx.x;
  o[t] = t < 512 ? a[t] : (t < 1024 ? b[t - 512] : c[t - 1024]);
}

__global__ void tr_f2b_k(const float* __restrict__ in, bf16* __restrict__ out, int R, int Cn)
{
  __shared__ float t[32][33];
  int c0 = blockIdx.x * 32, r0 = blockIdx.y * 32;
  int tx = threadIdx.x, ty = threadIdx.y;
#pragma unroll
  for (int i = 0; i < 32; i += 8) t[ty + i][tx] = in[(long)(r0 + ty + i) * Cn + c0 + tx];
  __syncthreads();
#pragma unroll
  for (int i = 0; i < 32; i += 8) out[(long)(c0 + ty + i) * R + r0 + tx] = (bf16)t[tx][ty + i];
}

__global__ void tr_b2b_k(const bf16* __restrict__ in, bf16* __restrict__ out, int R, int Cn)
{
  __shared__ bf16 t[32][34];
  int c0 = blockIdx.x * 32, r0 = blockIdx.y * 32;
  int tx = threadIdx.x, ty = threadIdx.y;
#pragma unroll
  for (int i = 0; i < 32; i += 8) t[ty + i][tx] = in[(long)(r0 + ty + i) * Cn + c0 + tx];
  __syncthreads();
#pragma unroll
  for (int i = 0; i < 32; i += 8) out[(long)(c0 + ty + i) * R + r0 + tx] = t[tx][ty + i];
}

// ---------------- host launch ----------------
extern "C" void kernel_launch(void* const* d_in, const int* in_sizes, int n_in,
                              void* d_out, int out_size, void* d_ws, size_t ws_size,
                              hipStream_t stream)
{
  const float* src = (const float*)d_in[0];
  const float* Wq  = (const float*)d_in[1];
  const float* bq  = (const float*)d_in[2];
  const float* Wk  = (const float*)d_in[3];
  const float* bk  = (const float*)d_in[4];
  const float* Wv  = (const float*)d_in[5];
  const float* bv  = (const float*)d_in[6];
  const float* Er  = (const float*)d_in[7];
  const float* W1  = (const float*)d_in[8];
  const float* b1  = (const float*)d_in[9];
  const float* W2  = (const float*)d_in[10];
  const float* b2  = (const float*)d_in[11];
  const float* g1  = (const float*)d_in[12];
  const float* be1 = (const float*)d_in[13];
  const float* g2  = (const float*)d_in[14];
  const float* be2 = (const float*)d_in[15];

  char* wp = (char*)d_ws;
  auto alloc = [&](size_t bytes) { char* p = wp; wp += (bytes + 255) & ~(size_t)255; return p; };

  bf16* x0b   = (bf16*)alloc((size_t)S * DMODEL * 2);
  bf16* wqkvT = (bf16*)alloc((size_t)3 * DMODEL * DMODEL * 2);
  float* bqkv = (float*)alloc((size_t)3 * DMODEL * 4);
  bf16* w1T   = (bf16*)alloc((size_t)DFF * DMODEL * 2);
  bf16* w2T   = (bf16*)alloc((size_t)DMODEL * DFF * 2);
  bf16* erS   = (bf16*)alloc((size_t)S * DH * 2);
  bf16* qkvb  = (bf16*)alloc((size_t)3 * S * DMODEL * 2);
  bf16* vt    = (bf16*)alloc((size_t)DMODEL * S * 2);
  bf16* qer   = (bf16*)alloc((size_t)NH * S * S * 2);
  float* pO   = (float*)alloc((size_t)NSP * NH * S * DH * 4);
  float* pM   = (float*)alloc((size_t)NSP * NH * S * 4);
  float* pL   = (float*)alloc((size_t)NSP * NH * S * 4);
  float* sa   = (float*)alloc((size_t)S * DMODEL * 4);
  bf16* yb    = (bf16*)alloc((size_t)2 * S * DMODEL * 2);
  bf16* h1    = (bf16*)alloc((size_t)2 * S * DFF * 2);
  float* pFF  = (float*)alloc((size_t)4 * 2 * S * DMODEL * 4);

  const long MN2 = (long)2 * S * DMODEL;
  dim3 tb(32, 8);

  conv_x0_k<<<(S * DMODEL) / 256, 256, 0, stream>>>(src, x0b);
  conv_er_k<<<(S * DH) / 256, 256, 0, stream>>>(Er, erS);
  tr_f2b_k<<<dim3(DMODEL / 32, DMODEL / 32), tb, 0, stream>>>(Wq, wqkvT, DMODEL, DMODEL);
  tr_f2b_k<<<dim3(DMODEL / 32, DMODEL / 32), tb, 0, stream>>>(Wk, wqkvT + DMODEL * DMODEL, DMODEL, DMODEL);
  tr_f2b_k<<<dim3(DMODEL / 32, DMODEL / 32), tb, 0, stream>>>(Wv, wqkvT + 2 * DMODEL * DMODEL, DMODEL, DMODEL);
  pack_bias_k<<<6, 256, 0, stream>>>(bq, bk, bv, bqkv);
  tr_f2b_k<<<dim3(DFF / 32, DMODEL / 32), tb, 0, stream>>>(W1, w1T, DMODEL, DFF);
  tr_f2b_k<<<dim3(DMODEL / 32, DFF / 32), tb, 0, stream>>>(W2, w2T, DFF, DMODEL);

  // QKV (batch 0 only), batched z=3
  gemm_k<<<dim3(4, 16, 3), 256, 0, stream>>>(
      x0b, 0, DMODEL, wqkvT, (long)DMODEL * DMODEL, DMODEL,
      qkvb, (long)S * DMODEL, DMODEL, bqkv, DMODEL, 2, S, DMODEL, DMODEL);

  const bf16* qb = qkvb;
  const bf16* kb = qkvb + (long)S * DMODEL;
  const bf16* vb = qkvb + (long)2 * S * DMODEL;

  // V^T
  tr_b2b_k<<<dim3(DMODEL / 32, S / 32), tb, 0, stream>>>(vb, vt, S, DMODEL);

  // QEr[h] = Q_h @ ErS^T
  gemm_k<<<dim3(16, 16, 8), 256, 0, stream>>>(
      qb, DH, DMODEL, erS, 0, DH, qer, (long)S * S, S, nullptr, 0, 2, S, S, DH);

  // fused attention
  attn_k<<<dim3(32 * NSP, NH), 256, 0, stream>>>(qb, kb, vt, qer, pO, pM, pL);
  merge_k<<<(S * DMODEL) / 256, 256, 0, stream>>>(pO, pM, pL, sa);

  // LN1 -> y (bf16)
  ln1_k<<<2 * S, 256, 0, stream>>>(src, sa, g1, be1, yb);

  // FFN1: y @ W1^T + b1, relu, bf16
  gemm_k<<<dim3(DFF / 128, (2 * S) / 128, 1), 256, 0, stream>>>(
      yb, 0, DMODEL, w1T, 0, DMODEL, h1, 0, DFF, b1, 0, 3, 2 * S, DFF, DMODEL);

  // FFN2 split-K=4: partials in pFF[z], bias added in ln2
  gemm_k<<<dim3(DMODEL / 128, (2 * S) / 128, 4), 256, 0, stream>>>(
      h1, 512, DFF, w2T, 512, DFF, pFF, MN2, DMODEL, nullptr, 0, 0, 2 * S, DMODEL, 512);

  // LN2 (+partial-sum +b2) -> out
  ln2_k<<<2 * S, 256, 0, stream>>>(yb, pFF, MN2, b2, g2, be2, (float*)d_out);
}